// Round 1
// baseline (350.506 us; speedup 1.0000x reference)
//
#include <hip/hip_runtime.h>
#include <math.h>

// DILATE / soft-DTW loss on MI355X.
// 512 independent soft-DTW problems (B=64, C=8), N=160.
// One workgroup per problem; anti-diagonal wavefront DP.
// Forward stores R (compact diagonal-major, N*N floats/problem) in d_ws
// (512*160*160*4 = 52.4 MB, fits L3). Backward recomputes D from the
// LDS-resident series and accumulates sum(E * (i-j)^2) without
// materializing E. Output: [loss, loss_shape(64), loss_temporal(64)].

#define NN 160
#define BC_TOT 512
#define B_SZ 64
#define C_SZ 8
#define GAMMA_F 0.01f
#define INVG 100.0f      // 1/gamma
#define BIGF 1e10f
#define NTHREADS 192     // 3 waves; threads 0..160 active in the DP

__global__ __launch_bounds__(NTHREADS)
void dtw_fb_kernel(const float* __restrict__ input,
                   const float* __restrict__ target,
                   float* __restrict__ Rg,      // BC_TOT * NN * NN floats
                   float* __restrict__ sdtw,    // BC_TOT floats
                   float* __restrict__ wlt)     // BC_TOT floats
{
    const int k   = blockIdx.x;
    const int tid = threadIdx.x;

    __shared__ float t_s[NN], p_s[NN];
    __shared__ float dbuf[3][NN + 1];   // rolling R diagonals (fwd & bwd)
    __shared__ float ebuf[3][NN + 1];   // rolling E diagonals (bwd)
    __shared__ float red[NTHREADS];

    const float* tg = target + (size_t)k * NN;
    const float* pg = input  + (size_t)k * NN;
    if (tid < NN) { t_s[tid] = tg[tid]; p_s[tid] = pg[tid]; }

    // init forward diag buffers: everything BIG, R[0][0]=0
    float* fb = (float*)dbuf;
    for (int idx = tid; idx < 3 * (NN + 1); idx += NTHREADS) fb[idx] = BIGF;
    __syncthreads();
    if (tid == 0) dbuf[0][0] = 0.0f;
    __syncthreads();

    float* Rk = Rg + (size_t)k * (NN * NN);

    // ---------------- forward DP ----------------
    // diag d = i + j, d in [2, 2N]; thread tid = row i.
    // buffers: cur = diag d, p1 = diag d-1, p2 = diag d-2 (indexed by i).
    int off = 0;  // running compact offset of diag d within Rk
    for (int d = 2; d <= 2 * NN; ++d) {
        const int imin = (1 > d - NN) ? 1 : d - NN;
        const int imax = (NN < d - 1) ? NN : d - 1;
        float*       cur = dbuf[d % 3];
        const float* p1  = dbuf[(d - 1) % 3];
        const float* p2  = dbuf[(d - 2) % 3];
        const int i = tid;
        if (i >= imin && i <= imax) {
            const int j = d - i;
            const float a = p2[i - 1];   // R[i-1][j-1]
            const float b = p1[i - 1];   // R[i-1][j]
            const float c = p1[i];       // R[i][j-1]
            const float m = fminf(a, fminf(b, c));
            const float s = expf((m - a) * INVG) + expf((m - b) * INVG)
                          + expf((m - c) * INVG);
            const float dt = t_s[i - 1] - p_s[j - 1];
            const float r  = dt * dt + m - GAMMA_F * logf(s);
            cur[i] = r;
            Rk[off + (i - imin)] = r;            // coalesced diag store
        } else if (i == 0 || i == d) {
            if (i <= NN) cur[i] = BIGF;          // row-0 / col-0 borders
        }
        off += imax - imin + 1;
        __syncthreads();
    }

    // sdtw value R[N][N] lives in diag-2N buffer, slot N
    if (tid == 0) sdtw[k] = dbuf[(2 * NN) % 3][NN];

    // zero E buffers (reads are predicate-guarded, but E at d=2N+1/2N+2
    // must be exactly 0)
    float* eb = (float*)ebuf;
    for (int idx = tid; idx < 3 * (NN + 1); idx += NTHREADS) eb[idx] = 0.0f;
    __syncthreads();

    // ---------------- backward (gradient) ----------------
    // E[i,j] = sum over successors (i+1,j), (i,j+1), (i+1,j+1) of
    //          E_succ * exp((R_succ - D_succ - R[i,j]) / gamma)
    // accumulate acc += E[i,j] * (i-j)^2 on the fly.
    float acc  = 0.0f;
    int   offd = NN * NN;
    float rnext = 0.0f;
    {   // prefetch diag 2N
        const int d = 2 * NN;
        const int imin = (1 > d - NN) ? 1 : d - NN;
        const int imax = (NN < d - 1) ? NN : d - 1;
        offd -= (imax - imin + 1);
        if (tid >= imin && tid <= imax) rnext = Rk[offd + tid - imin];
    }
    for (int d = 2 * NN; d >= 2; --d) {
        const int imin = (1 > d - NN) ? 1 : d - NN;
        const int imax = (NN < d - 1) ? NN : d - 1;
        float*       Rc = dbuf[d % 3];
        const float* R1 = dbuf[(d + 1) % 3];
        const float* R2 = dbuf[(d + 2) % 3];
        float*       Ec = ebuf[d % 3];
        const float* E1 = ebuf[(d + 1) % 3];
        const float* E2 = ebuf[(d + 2) % 3];
        const int  i = tid;
        const float r = rnext;
        const bool active = (i >= imin && i <= imax);
        if (active) Rc[i] = r;
        // prefetch next diagonal early (latency hidden under exp/LDS work)
        if (d > 2) {
            const int dn  = d - 1;
            const int imn = (1 > dn - NN) ? 1 : dn - NN;
            const int imx = (NN < dn - 1) ? NN : dn - 1;
            offd -= (imx - imn + 1);
            if (tid >= imn && tid <= imx) rnext = Rk[offd + tid - imn];
        }
        if (active) {
            const int j = d - i;
            float e;
            if (i == NN && j == NN) {
                e = 1.0f;
            } else {
                e = 0.0f;
                if (i + 1 <= NN) {              // up successor (i+1, j)
                    const float dd = t_s[i] - p_s[j - 1];
                    e += E1[i + 1] * expf((R1[i + 1] - dd * dd - r) * INVG);
                }
                if (j + 1 <= NN) {              // left successor (i, j+1)
                    const float dd = t_s[i - 1] - p_s[j];
                    e += E1[i] * expf((R1[i] - dd * dd - r) * INVG);
                }
                if (i + 1 <= NN && j + 1 <= NN) { // diag successor (i+1, j+1)
                    const float dd = t_s[i] - p_s[j];
                    e += E2[i + 1] * expf((R2[i + 1] - dd * dd - r) * INVG);
                }
            }
            Ec[i] = e;
            const float dij = (float)(i - j);
            acc += e * dij * dij;
        }
        __syncthreads();
    }

    // block reduce acc -> wlt[k] = sum(E*Omega) / N^2
    red[tid] = acc;
    __syncthreads();
    if (tid < 64) {
        float v = red[tid] + red[tid + 64] + red[tid + 128];
        #pragma unroll
        for (int o = 32; o > 0; o >>= 1) v += __shfl_down(v, o);
        if (tid == 0) wlt[k] = v * (1.0f / (NN * NN));
    }
}

// final reduction: per-batch means + scalar loss. One wave (64 threads = B).
__global__ __launch_bounds__(64)
void finalize_kernel(const float* __restrict__ sdtw,
                     const float* __restrict__ wlt,
                     float* __restrict__ out)
{
    const int b = threadIdx.x;   // 0..63
    float ls = 0.0f, lt = 0.0f;
    #pragma unroll
    for (int c = 0; c < C_SZ; ++c) {
        ls += sdtw[b * C_SZ + c];
        lt += wlt[b * C_SZ + c];
    }
    ls *= (1.0f / C_SZ);
    lt *= (1.0f / C_SZ);
    out[1 + b]        = ls;   // loss_shape
    out[1 + B_SZ + b] = lt;   // loss_temporal
    float v = 0.5f * ls + 0.5f * lt;
    #pragma unroll
    for (int o = 32; o > 0; o >>= 1) v += __shfl_down(v, o);
    if (b == 0) out[0] = v * (1.0f / B_SZ);
}

extern "C" void kernel_launch(void* const* d_in, const int* in_sizes, int n_in,
                              void* d_out, int out_size, void* d_ws, size_t ws_size,
                              hipStream_t stream) {
    const float* input  = (const float*)d_in[0];   // p (B,C,N)
    const float* target = (const float*)d_in[1];   // t (B,C,N)
    float* out = (float*)d_out;                    // 129 floats

    // ws layout: Rg [512*160*160] | sdtw [512] | wlt [512]  (~52.4 MB)
    float* Rg   = (float*)d_ws;
    float* sdtw = Rg + (size_t)BC_TOT * NN * NN;
    float* wlt  = sdtw + BC_TOT;

    dtw_fb_kernel<<<BC_TOT, NTHREADS, 0, stream>>>(input, target, Rg, sdtw, wlt);
    finalize_kernel<<<1, 64, 0, stream>>>(sdtw, wlt, out);
}